// Round 2
// 1041.027 us; speedup vs baseline: 1.0404x; 1.0404x over previous
//
#include <hip/hip_runtime.h>

typedef __attribute__((ext_vector_type(8))) __bf16 bf16x8;
typedef __attribute__((ext_vector_type(4))) float f32x4;
typedef __attribute__((ext_vector_type(4))) unsigned int u32x4;

#define MFMA16(a, b, c) __builtin_amdgcn_mfma_f32_16x16x32_bf16((a), (b), (c), 0, 0, 0)
#define LOG2E 1.4426950408889634f

constexpr int S_LEN = 2048;
constexpr int DIM   = 64;
constexpr int QT    = 16;   // q rows per block
constexpr int KT    = 64;   // k rows per tile (16 cols per wave x 4 waves)
constexpr int NBH   = 32;   // B*H
constexpr size_t HELEMS = (size_t)NBH * S_LEN * DIM;   // 4Mi elements

__device__ __forceinline__ __bf16 bfbits(unsigned int b) {
    union { unsigned short s; __bf16 h; } c; c.s = (unsigned short)b; return c.h;
}
__device__ __forceinline__ unsigned short bits_of(__bf16 h) {
    union { __bf16 h; unsigned short s; } c; c.h = h; return c.s;
}
__device__ __forceinline__ unsigned int packbf(float x) {
    __bf16 h = (__bf16)x;
    __bf16 l = (__bf16)(x - (float)h);
    return (unsigned int)bits_of(h) | ((unsigned int)bits_of(l) << 16);
}

// ================= prep kernels =================

// one wave per K row: normalized split-bf16 K (norm folded in), row-major [s][d]
__global__ void kprep_kernel(const float* __restrict__ kg, __bf16* __restrict__ khi,
                             __bf16* __restrict__ klo) {
    int gw   = (blockIdx.x * blockDim.x + threadIdx.x) >> 6;
    int lane = threadIdx.x & 63;
    float x  = kg[(size_t)gw * DIM + lane];
    float ss = x * x;
#pragma unroll
    for (int off = 1; off < 64; off <<= 1) ss += __shfl_xor(ss, off);
    float ik = 1.0f / fmaxf(sqrtf(ss), 1e-12f);
    float xn = x * ik;
    __bf16 h = (__bf16)xn;
    khi[(size_t)gw * DIM + lane] = h;
    klo[(size_t)gw * DIM + lane] = (__bf16)(xn - (float)h);
}

// V -> transposed split planes vThi/vTlo [bh][d][s] (bf16 hi and residual-lo)
__global__ void vprep_kernel(const float* __restrict__ vg, __bf16* __restrict__ vThi,
                             __bf16* __restrict__ vTlo) {
    __shared__ unsigned int t[64][65];
    const int bh  = blockIdx.y;
    const int s0  = blockIdx.x * 64;
    const int tid = threadIdx.x;
    const size_t hbase = (size_t)bh * S_LEN * DIM;
#pragma unroll
    for (int e = 0; e < 4; ++e) {
        int idx = tid * 4 + e * 1024;
        int r = idx >> 6, d = idx & 63;
        float4 x = *(const float4*)(vg + hbase + (size_t)(s0 + r) * DIM + d);
        t[r][d]     = packbf(x.x);
        t[r][d + 1] = packbf(x.y);
        t[r][d + 2] = packbf(x.z);
        t[r][d + 3] = packbf(x.w);
    }
    __syncthreads();
#pragma unroll
    for (int e = 0; e < 8; ++e) {
        int pi = tid + e * 256;
        int d = pi >> 5, r = (pi & 31) * 2;
        unsigned int a = t[r][d], b = t[r + 1][d];
        unsigned int hi = (a & 0xffffu) | (b << 16);
        unsigned int lo = (a >> 16) | (b & 0xffff0000u);
        *(unsigned int*)(vThi + hbase + (size_t)d * S_LEN + s0 + r) = hi;
        *(unsigned int*)(vTlo + hbase + (size_t)d * S_LEN + s0 + r) = lo;
    }
}

// ================= main fused attention =================
__global__ __launch_bounds__(256, 4)
void attn2_kernel(const float* __restrict__ qg, const __bf16* __restrict__ khi,
                  const __bf16* __restrict__ klo, const __bf16* __restrict__ vThi,
                  const __bf16* __restrict__ vTlo,
                  float* __restrict__ outg, float* __restrict__ scoreg) {
    // [buf][plane][d-row 64][s-col 64] bf16, 16B-block XOR-swizzled columns
    __shared__ __align__(16) unsigned short vstage[2][2][64][64];   // 32 KB
    __shared__ unsigned int pstage[QT * 68];                        // packed P hi/lo
    __shared__ float sinvq[QT];
    __shared__ float sinvl[QT];
    __shared__ float redbuf[4][QT];

    const int bh   = blockIdx.y;
    const int q0   = blockIdx.x * QT;
    const int tid  = threadIdx.x;
    const int lane = tid & 63;
    const int wv   = tid >> 6;     // wave 0..3
    const int quad = lane >> 4;    // 0..3
    const int l16  = lane & 15;

    const size_t hbase = (size_t)bh * S_LEN * DIM;

    // per-lane V staging source offsets (kt-invariant); inverse-swizzled source,
    // linear LDS dest (global_load_lds writes base + lane*16B)
    int voff[4];
#pragma unroll
    for (int e = 0; e < 4; ++e) {
        int b   = e * 4096 + wv * 1024 + lane * 16;   // byte offset within one buf
        int row = (b >> 7) & 63;                      // d-row within plane
        int cbR = ((b >> 4) & 7) ^ (row & 7);         // raw 16B-block (8 bf16) index
        voff[e] = row * S_LEN + cbR * 8;              // element offset within plane/head
    }

    // ---- q-row inverse norms, folded with 1/temperature ----
    {
        int row = tid >> 4, c = tid & 15;
        const float* p = qg + hbase + (size_t)(q0 + row) * DIM;
        float ss = 0.f;
#pragma unroll
        for (int j = 0; j < 4; ++j) { float x = p[c + 16 * j]; ss += x * x; }
#pragma unroll
        for (int off = 1; off < 16; off <<= 1) ss += __shfl_xor(ss, off);
        if (c == 0) sinvq[row] = 10.0f / fmaxf(sqrtf(ss), 1e-12f);
    }
    __syncthreads();

    // ---- Q A-fragments (m=l16, k=quad*8+j), split hi/lo ----
    bf16x8 aqh[2], aql[2];
    {
        const float* qr = qg + hbase + (size_t)(q0 + l16) * DIM;
        float iq = sinvq[l16];
#pragma unroll
        for (int ks = 0; ks < 2; ++ks) {
            const float* p = qr + ks * 32 + quad * 8;
            float4 x0 = *(const float4*)(p);
            float4 x1 = *(const float4*)(p + 4);
            float xs[8] = {x0.x, x0.y, x0.z, x0.w, x1.x, x1.y, x1.z, x1.w};
#pragma unroll
            for (int j = 0; j < 8; ++j) {
                float x = xs[j] * iq;
                __bf16 h = (__bf16)x;
                aqh[ks][j] = h;
                aql[ks][j] = (__bf16)(x - (float)h);
            }
        }
    }

    // ---- prologue: stage V tile 0 into buf 0 (drains at first barrier) ----
#pragma unroll
    for (int e = 0; e < 4; ++e) {
        const __bf16* srcp = (e < 2) ? vThi : vTlo;
        __builtin_amdgcn_global_load_lds(
            (const __attribute__((address_space(1))) unsigned int*)(srcp + hbase + voff[e]),
            (__attribute__((address_space(3))) unsigned int*)((char*)&vstage[0][0][0][0] + e * 4096 + wv * 1024),
            16, 0, 0);
    }

    // per-lane K fragment base offset
    const size_t koff = hbase + (size_t)(wv * 16 + l16) * DIM + quad * 8;

    // ---- pass 1: row sums of exp(s - 10) ----
    bf16x8 ch0, ch1, cl0, cl1;
    {
        const __bf16* ph = khi + koff;
        const __bf16* pl = klo + koff;
        ch0 = *(const bf16x8*)(ph); ch1 = *(const bf16x8*)(ph + 32);
        cl0 = *(const bf16x8*)(pl); cl1 = *(const bf16x8*)(pl + 32);
    }
    float lacc[4] = {0.f, 0.f, 0.f, 0.f};
    for (int kt = 0; kt < S_LEN; kt += KT) {
        f32x4 a0 = {0.f, 0.f, 0.f, 0.f}, a1 = {0.f, 0.f, 0.f, 0.f};
        a0 = MFMA16(aqh[0], ch0, a0);
        a0 = MFMA16(aqh[0], cl0, a0);
        a0 = MFMA16(aql[0], ch0, a0);
        a1 = MFMA16(aqh[1], ch1, a1);
        a1 = MFMA16(aqh[1], cl1, a1);
        a1 = MFMA16(aql[1], ch1, a1);
        if (kt + KT < S_LEN) {   // reload same regs; latency overlaps exp/next MFMA wait
            const __bf16* ph = khi + koff + (size_t)(kt + KT) * DIM;
            const __bf16* pl = klo + koff + (size_t)(kt + KT) * DIM;
            ch0 = *(const bf16x8*)(ph); ch1 = *(const bf16x8*)(ph + 32);
            cl0 = *(const bf16x8*)(pl); cl1 = *(const bf16x8*)(pl + 32);
        }
        f32x4 sv = a0 + a1;
#pragma unroll
        for (int r = 0; r < 4; ++r) lacc[r] += exp2f((sv[r] - 10.0f) * LOG2E);
    }
    // reload K tile 0 for pass 2 (overlaps reduction + barriers)
    {
        const __bf16* ph = khi + koff;
        const __bf16* pl = klo + koff;
        ch0 = *(const bf16x8*)(ph); ch1 = *(const bf16x8*)(ph + 32);
        cl0 = *(const bf16x8*)(pl); cl1 = *(const bf16x8*)(pl + 32);
    }
#pragma unroll
    for (int r = 0; r < 4; ++r) {
#pragma unroll
        for (int off = 1; off < 16; off <<= 1) lacc[r] += __shfl_xor(lacc[r], off);
    }
    if (l16 == 0) {
#pragma unroll
        for (int r = 0; r < 4; ++r) redbuf[wv][quad * 4 + r] = lacc[r];
    }
    __syncthreads();
    if (tid < QT) {
        float l = redbuf[0][tid] + redbuf[1][tid] + redbuf[2][tid] + redbuf[3][tid];
        sinvl[tid] = 1.0f / l;
    }
    __syncthreads();

    float il[4];
#pragma unroll
    for (int r = 0; r < 4; ++r) il[r] = sinvl[quad * 4 + r];

    // ---- pass 2: recompute s, write score, accumulate O = P.V ----
    f32x4 o0 = {0.f, 0.f, 0.f, 0.f}, o1 = {0.f, 0.f, 0.f, 0.f};
    float* srow = scoreg + (size_t)bh * S_LEN * S_LEN;
    const int nrow = wv * 16 + l16;
    int buf = 0;

    for (int kt = 0; kt < S_LEN; kt += KT) {
        if (kt + KT < S_LEN) {
            // stage next V tile into buf^1 (latency hides under QK + softmax)
#pragma unroll
            for (int e = 0; e < 4; ++e) {
                const __bf16* srcp = (e < 2) ? vThi : vTlo;
                __builtin_amdgcn_global_load_lds(
                    (const __attribute__((address_space(1))) unsigned int*)(srcp + hbase + (kt + KT) + voff[e]),
                    (__attribute__((address_space(3))) unsigned int*)((char*)&vstage[buf ^ 1][0][0][0] + e * 4096 + wv * 1024),
                    16, 0, 0);
            }
        }
        f32x4 a0 = {0.f, 0.f, 0.f, 0.f}, a1 = {0.f, 0.f, 0.f, 0.f};
        a0 = MFMA16(aqh[0], ch0, a0);
        a0 = MFMA16(aqh[0], cl0, a0);
        a0 = MFMA16(aql[0], ch0, a0);
        a1 = MFMA16(aqh[1], ch1, a1);
        a1 = MFMA16(aqh[1], cl1, a1);
        a1 = MFMA16(aql[1], ch1, a1);
        if (kt + KT < S_LEN) {   // reload same regs; hides under PV + barriers
            const __bf16* ph = khi + koff + (size_t)(kt + KT) * DIM;
            const __bf16* pl = klo + koff + (size_t)(kt + KT) * DIM;
            ch0 = *(const bf16x8*)(ph); ch1 = *(const bf16x8*)(ph + 32);
            cl0 = *(const bf16x8*)(pl); cl1 = *(const bf16x8*)(pl + 32);
        }
        f32x4 sv = a0 + a1;
        int ncol = kt + wv * 16 + l16;
#pragma unroll
        for (int r = 0; r < 4; ++r) {
            float pv = exp2f((sv[r] - 10.0f) * LOG2E) * il[r];
            srow[(size_t)(q0 + quad * 4 + r) * S_LEN + ncol] = pv;     // score store
            pstage[(quad * 4 + r) * 68 + wv * 16 + l16] = packbf(pv);  // packed transpose
        }
        __syncthreads();
        // P.V: A = p (m=l16, k=quad*8+j), B = v (n=nrow), B read = direct bf16x8
#pragma unroll
        for (int ks = 0; ks < 2; ++ks) {
            const u32x4* pp = (const u32x4*)&pstage[l16 * 68 + ks * 32 + quad * 8];
            u32x4 pu0 = pp[0], pu1 = pp[1];
            bf16x8 ph_, pl_;
#pragma unroll
            for (int j = 0; j < 4; ++j) {
                ph_[j]     = bfbits(pu0[j]); pl_[j]     = bfbits(pu0[j] >> 16);
                ph_[j + 4] = bfbits(pu1[j]); pl_[j + 4] = bfbits(pu1[j] >> 16);
            }
            int cb = (((ks * 4 + quad) ^ (l16 & 7)) << 3);
            bf16x8 vh_ = *(const bf16x8*)&vstage[buf][0][nrow][cb];
            bf16x8 vl_ = *(const bf16x8*)&vstage[buf][1][nrow][cb];
            if (ks == 0) {
                o0 = MFMA16(ph_, vh_, o0);
                o0 = MFMA16(ph_, vl_, o0);
                o0 = MFMA16(pl_, vh_, o0);
            } else {
                o1 = MFMA16(ph_, vh_, o1);
                o1 = MFMA16(ph_, vl_, o1);
                o1 = MFMA16(pl_, vh_, o1);
            }
        }
        __syncthreads();
        buf ^= 1;
    }

    f32x4 o = o0 + o1;
#pragma unroll
    for (int r = 0; r < 4; ++r)
        outg[hbase + (size_t)(q0 + quad * 4 + r) * DIM + wv * 16 + l16] = o[r];
}

// ================= fallback path (verified 1083 us kernel, verbatim) =================

__global__ void knorm_kernel(const float* __restrict__ kg, float* __restrict__ invk) {
    int gw   = (blockIdx.x * blockDim.x + threadIdx.x) >> 6;
    int lane = threadIdx.x & 63;
    float x  = kg[(size_t)gw * DIM + lane];
    float ss = x * x;
#pragma unroll
    for (int off = 1; off < 64; off <<= 1) ss += __shfl_xor(ss, off);
    if (lane == 0) invk[gw] = 1.0f / fmaxf(sqrtf(ss), 1e-12f);
}

__device__ __forceinline__ f32x4 qk_tile(const float* __restrict__ kr, float ik,
                                         const bf16x8* aqh, const bf16x8* aql, int quad) {
    f32x4 a0 = {0.f, 0.f, 0.f, 0.f}, a1 = {0.f, 0.f, 0.f, 0.f};
#pragma unroll
    for (int ks = 0; ks < 2; ++ks) {
        const float* p = kr + ks * 32 + quad * 8;
        float4 x0 = *(const float4*)(p);
        float4 x1 = *(const float4*)(p + 4);
        float xs[8] = {x0.x, x0.y, x0.z, x0.w, x1.x, x1.y, x1.z, x1.w};
        bf16x8 bh_, bl_;
#pragma unroll
        for (int j = 0; j < 8; ++j) {
            float x = xs[j] * ik;
            __bf16 h = (__bf16)x;
            bh_[j] = h;
            bl_[j] = (__bf16)(x - (float)h);
        }
        if (ks == 0) {
            a0 = MFMA16(aqh[0], bh_, a0);
            a0 = MFMA16(aqh[0], bl_, a0);
            a0 = MFMA16(aql[0], bh_, a0);
        } else {
            a1 = MFMA16(aqh[1], bh_, a1);
            a1 = MFMA16(aqh[1], bl_, a1);
            a1 = MFMA16(aql[1], bh_, a1);
        }
    }
    return a0 + a1;
}

__global__ __launch_bounds__(256, 4)
void attn_kernel(const float* __restrict__ qg, const float* __restrict__ kg,
                 const float* __restrict__ vg, const float* __restrict__ invk,
                 float* __restrict__ outg, float* __restrict__ scoreg) {
    __shared__ float vstage[KT * 65];
    __shared__ float pstage[QT * 65];
    __shared__ float sinvk[S_LEN];
    __shared__ float sinvq[QT];
    __shared__ float sinvl[QT];
    __shared__ float redbuf[4][QT];

    const int bh   = blockIdx.y;
    const int q0   = blockIdx.x * QT;
    const int tid  = threadIdx.x;
    const int lane = tid & 63;
    const int wv   = tid >> 6;
    const int quad = lane >> 4;
    const int l16  = lane & 15;

    const size_t hbase = (size_t)bh * S_LEN * DIM;

    for (int i = tid; i < S_LEN; i += 256) sinvk[i] = invk[bh * S_LEN + i];

    {
        int row = tid >> 4, c = tid & 15;
        const float* p = qg + hbase + (size_t)(q0 + row) * DIM;
        float ss = 0.f;
#pragma unroll
        for (int j = 0; j < 4; ++j) { float x = p[c + 16 * j]; ss += x * x; }
#pragma unroll
        for (int off = 1; off < 16; off <<= 1) ss += __shfl_xor(ss, off);
        if (c == 0) sinvq[row] = 10.0f / fmaxf(sqrtf(ss), 1e-12f);
    }
    __syncthreads();

    bf16x8 aqh[2], aql[2];
    {
        const float* qr = qg + hbase + (size_t)(q0 + l16) * DIM;
        float iq = sinvq[l16];
#pragma unroll
        for (int ks = 0; ks < 2; ++ks) {
            const float* p = qr + ks * 32 + quad * 8;
            float4 x0 = *(const float4*)(p);
            float4 x1 = *(const float4*)(p + 4);
            float xs[8] = {x0.x, x0.y, x0.z, x0.w, x1.x, x1.y, x1.z, x1.w};
#pragma unroll
            for (int j = 0; j < 8; ++j) {
                float x = xs[j] * iq;
                __bf16 h = (__bf16)x;
                aqh[ks][j] = h;
                aql[ks][j] = (__bf16)(x - (float)h);
            }
        }
    }

    float lacc[4] = {0.f, 0.f, 0.f, 0.f};
    for (int kt = 0; kt < S_LEN; kt += KT) {
        int ncol = kt + wv * 16 + l16;
        const float* kr = kg + hbase + (size_t)ncol * DIM;
        f32x4 sv = qk_tile(kr, sinvk[ncol], aqh, aql, quad);
#pragma unroll
        for (int r = 0; r < 4; ++r) lacc[r] += exp2f((sv[r] - 10.0f) * LOG2E);
    }
#pragma unroll
    for (int r = 0; r < 4; ++r) {
#pragma unroll
        for (int off = 1; off < 16; off <<= 1) lacc[r] += __shfl_xor(lacc[r], off);
    }
    if (l16 == 0) {
#pragma unroll
        for (int r = 0; r < 4; ++r) redbuf[wv][quad * 4 + r] = lacc[r];
    }
    __syncthreads();
    if (tid < QT) {
        float l = redbuf[0][tid] + redbuf[1][tid] + redbuf[2][tid] + redbuf[3][tid];
        sinvl[tid] = 1.0f / l;
    }
    __syncthreads();

    float il[4];
#pragma unroll
    for (int r = 0; r < 4; ++r) il[r] = sinvl[quad * 4 + r];

    f32x4 o0 = {0.f, 0.f, 0.f, 0.f}, o1 = {0.f, 0.f, 0.f, 0.f};
    float* srow = scoreg + (size_t)bh * S_LEN * S_LEN;

    for (int kt = 0; kt < S_LEN; kt += KT) {
        const float* vt = vg + hbase + (size_t)kt * DIM;
#pragma unroll
        for (int e = 0; e < 16; ++e) {
            int i = tid + 256 * e;
            vstage[(i >> 6) * 65 + (i & 63)] = vt[i];
        }
        int ncol = kt + wv * 16 + l16;
        const float* kr = kg + hbase + (size_t)ncol * DIM;
        f32x4 sv = qk_tile(kr, sinvk[ncol], aqh, aql, quad);
        float pv[4];
#pragma unroll
        for (int r = 0; r < 4; ++r) {
            pv[r] = exp2f((sv[r] - 10.0f) * LOG2E) * il[r];
            srow[(size_t)(q0 + quad * 4 + r) * S_LEN + ncol] = pv[r];
            pstage[(quad * 4 + r) * 65 + wv * 16 + l16] = pv[r];
        }
        __syncthreads();
#pragma unroll
        for (int ks = 0; ks < 2; ++ks) {
            bf16x8 ph, pl, vh, vl;
#pragma unroll
            for (int j = 0; j < 8; ++j) {
                int kk = ks * 32 + quad * 8 + j;
                float pp = pstage[l16 * 65 + kk];
                __bf16 h = (__bf16)pp;
                ph[j] = h;
                pl[j] = (__bf16)(pp - (float)h);
                float vv = vstage[kk * 65 + wv * 16 + l16];
                h = (__bf16)vv;
                vh[j] = h;
                vl[j] = (__bf16)(vv - (float)h);
            }
            if (ks == 0) {
                o0 = MFMA16(ph, vh, o0);
                o0 = MFMA16(ph, vl, o0);
                o0 = MFMA16(pl, vh, o0);
            } else {
                o1 = MFMA16(ph, vh, o1);
                o1 = MFMA16(ph, vl, o1);
                o1 = MFMA16(pl, vh, o1);
            }
        }
        __syncthreads();
    }

    f32x4 o = o0 + o1;
#pragma unroll
    for (int r = 0; r < 4; ++r)
        outg[hbase + (size_t)(q0 + quad * 4 + r) * DIM + wv * 16 + l16] = o[r];
}

// ================= launcher =================
extern "C" void kernel_launch(void* const* d_in, const int* in_sizes, int n_in,
                              void* d_out, int out_size, void* d_ws, size_t ws_size,
                              hipStream_t stream) {
    const float* q = (const float*)d_in[0];
    const float* k = (const float*)d_in[1];
    const float* v = (const float*)d_in[2];
    float* out   = (float*)d_out;
    float* score = out + (size_t)NBH * S_LEN * DIM;

    constexpr size_t NEED = HELEMS * 8;   // khi+klo+vThi+vTlo, 2 B each = 32 MB
    if (ws_size >= NEED) {
        __bf16* khi  = (__bf16*)d_ws;
        __bf16* klo  = khi + HELEMS;
        __bf16* vThi = klo + HELEMS;
        __bf16* vTlo = vThi + HELEMS;
        kprep_kernel<<<dim3(NBH * S_LEN / 4), 256, 0, stream>>>(k, khi, klo);
        vprep_kernel<<<dim3(S_LEN / 64, NBH), 256, 0, stream>>>(v, vThi, vTlo);
        attn2_kernel<<<dim3(S_LEN / QT, NBH), 256, 0, stream>>>(q, khi, klo, vThi, vTlo, out, score);
    } else {
        float* invk = (float*)d_ws;   // NBH*S_LEN floats = 256 KB
        knorm_kernel<<<dim3(NBH * S_LEN / 4), 256, 0, stream>>>(k, invk);
        attn_kernel<<<dim3(S_LEN / QT, NBH), 256, 0, stream>>>(q, k, v, invk, out, score);
    }
}